// Round 14
// baseline (453.991 us; speedup 1.0000x reference)
//
#include <hip/hip_runtime.h>

typedef unsigned short u16;
typedef __attribute__((ext_vector_type(8))) short short8;
typedef __attribute__((ext_vector_type(4))) unsigned short u16x4;
typedef __attribute__((ext_vector_type(4))) float f32x4;

#define DEV __device__ __forceinline__
#define VMW(n) asm volatile("s_waitcnt vmcnt(" #n ")" ::: "memory")

DEV float bf2f(u16 u) { return __uint_as_float(((unsigned int)u) << 16); }
DEV u16 f2bf(float f) {
  unsigned int u = __float_as_uint(f);
  u += 0x7FFF + ((u >> 16) & 1);
  return (u16)(u >> 16);
}

DEV float redmax16(float v) {
  v = fmaxf(v, __shfl_xor(v, 1));
  v = fmaxf(v, __shfl_xor(v, 2));
  v = fmaxf(v, __shfl_xor(v, 4));
  v = fmaxf(v, __shfl_xor(v, 8));
  return v;
}
DEV float redsum16(float v) {
  v += __shfl_xor(v, 1);
  v += __shfl_xor(v, 2);
  v += __shfl_xor(v, 4);
  v += __shfl_xor(v, 8);
  return v;
}

// ---------------- transpose + cast f32 -> bf16, 32x32 tiles ----------------
__global__ __launch_bounds__(256) void transpose_f32_bf16(const float* __restrict__ in,
                                                          u16* __restrict__ out,
                                                          int R, int C) {
  __shared__ u16 tile[32][33];
  int tx = threadIdx.x & 31, ty = threadIdx.x >> 5;  // 32 x 8
  int r0 = blockIdx.y * 32, c0 = blockIdx.x * 32;
#pragma unroll
  for (int i = 0; i < 32; i += 8)
    tile[ty + i][tx] = f2bf(in[(size_t)(r0 + ty + i) * C + c0 + tx]);
  __syncthreads();
#pragma unroll
  for (int i = 0; i < 32; i += 8)
    out[(size_t)(c0 + ty + i) * R + r0 + tx] = tile[tx][ty + i];
}

// ---------------- transpose V third of qkv -> vT[b,h][64][4096] -------------
__global__ __launch_bounds__(256) void transpose_v(const u16* __restrict__ qkv,
                                                   u16* __restrict__ vT) {
  __shared__ u16 tile[32][33];
  int tx = threadIdx.x & 31, ty = threadIdx.x >> 5;  // 32 x 8
  int s0 = blockIdx.x * 32, d0 = blockIdx.y * 32;
  int bh = blockIdx.z;
  const u16* src = qkv + (size_t)(bh >> 4) * 4096 * 3072 + 2048 + (bh & 15) * 64;
#pragma unroll
  for (int i = 0; i < 32; i += 8)
    tile[ty + i][tx] = src[(size_t)(s0 + ty + i) * 3072 + d0 + tx];
  __syncthreads();
  u16* dst = vT + (size_t)bh * 64 * 4096;
#pragma unroll
  for (int i = 0; i < 32; i += 8)
    dst[(size_t)(d0 + ty + i) * 4096 + s0 + tx] = tile[tx][ty + i];
}

// ---------------- RMSNorm: 8192 rows x 1024, f32 in -> bf16 out ----------------
__global__ __launch_bounds__(256) void rmsnorm_kernel(const float* __restrict__ x,
                                                      const float* __restrict__ w,
                                                      u16* __restrict__ xn) {
  int row = blockIdx.x, t = threadIdx.x;
  const float4* xr = reinterpret_cast<const float4*>(x + (size_t)row * 1024);
  float4 v = xr[t];
  float ss = v.x * v.x + v.y * v.y + v.z * v.z + v.w * v.w;
#pragma unroll
  for (int d = 1; d < 64; d <<= 1) ss += __shfl_xor(ss, d);
  __shared__ float red[4];
  if ((t & 63) == 0) red[t >> 6] = ss;
  __syncthreads();
  float tot = red[0] + red[1] + red[2] + red[3];
  float inv = rsqrtf(tot * (1.0f / 1024.0f) + 1e-6f);
  float4 wv = reinterpret_cast<const float4*>(w)[t];
  u16x4 o;
  o[0] = f2bf(v.x * inv * wv.x);
  o[1] = f2bf(v.y * inv * wv.y);
  o[2] = f2bf(v.z * inv * wv.z);
  o[3] = f2bf(v.w * inv * wv.w);
  *reinterpret_cast<u16x4*>(xn + (size_t)row * 1024 + t * 4) = o;
}

// ------- RoPE in-place, vectorized: one block per qkv row; q scaled 0.125 ----
__global__ __launch_bounds__(256) void rope_kernel(u16* __restrict__ qkv,
                                                   const float* __restrict__ sp,
                                                   const float* __restrict__ cp) {
  int row = blockIdx.x;  // 8192 rows
  int t = threadIdx.x;
  int pos = row & 4095;
  int e0 = t * 8;
  float sc = (e0 < 1024) ? 0.125f : 1.0f;  // fold 1/sqrt(64) into q (exact)
  int d0 = e0 & 63;
  u16* p = qkv + (size_t)row * 3072 + e0;
  short8 v = *reinterpret_cast<const short8*>(p);
  float4 s01 = *reinterpret_cast<const float4*>(sp + pos * 64 + d0);
  float4 s23 = *reinterpret_cast<const float4*>(sp + pos * 64 + d0 + 4);
  float4 c01 = *reinterpret_cast<const float4*>(cp + pos * 64 + d0);
  float4 c23 = *reinterpret_cast<const float4*>(cp + pos * 64 + d0 + 4);
  short8 o;
  float xe, xo;
  xe = bf2f((u16)v[0]); xo = bf2f((u16)v[1]);
  o[0] = (short)f2bf((xe * c01.x - xo * s01.x) * sc);
  o[1] = (short)f2bf((xo * c01.y + xe * s01.y) * sc);
  xe = bf2f((u16)v[2]); xo = bf2f((u16)v[3]);
  o[2] = (short)f2bf((xe * c01.z - xo * s01.z) * sc);
  o[3] = (short)f2bf((xo * c01.w + xe * s01.w) * sc);
  xe = bf2f((u16)v[4]); xo = bf2f((u16)v[5]);
  o[4] = (short)f2bf((xe * c23.x - xo * s23.x) * sc);
  o[5] = (short)f2bf((xo * c23.y + xe * s23.y) * sc);
  xe = bf2f((u16)v[6]); xo = bf2f((u16)v[7]);
  o[6] = (short)f2bf((xe * c23.z - xo * s23.z) * sc);
  o[7] = (short)f2bf((xo * c23.w + xe * s23.w) * sc);
  *reinterpret_cast<short8*>(p) = o;
}

// ============ Pipelined GEMM (bench-R5/R9 exact): all three GEMMs ===========
// BM=256, BN=128, BK=64; 8 waves (4M x 2N). Triple-buffered LDS (144 KB),
// staging 1 tile ahead, counted vmcnt(6) at tile boundary, setprio, raw
// s_barrier, XOR-swizzled rows. mode 0: bf16; 1: bf16+GELU; 2: f32.
DEV void stage_half(const u16* __restrict__ gbase, int K, int kt, char* dst, int w, int l) {
#pragma unroll
  for (int j = 0; j < 2; ++j) {
    int s = w * 2 + j;
    int row = s * 8 + (l >> 3);
    int ksrc = ((l & 7) ^ (l >> 3)) << 3;
    const u16* src = gbase + (size_t)row * K + kt + ksrc;
    __builtin_amdgcn_global_load_lds(
        (const __attribute__((address_space(1))) unsigned int*)src,
        (__attribute__((address_space(3))) unsigned int*)(dst + s * 1024 + l * 16),
        16, 0, 0);
  }
}

DEV short8 ldfrag(const char* base, int row, int slot) {
  return *reinterpret_cast<const short8*>(base + row * 128 + (((slot ^ (row & 7)) << 4)));
}

__global__ __launch_bounds__(512) void gemm256(const u16* __restrict__ A,
                                               const u16* __restrict__ BT,
                                               const float* __restrict__ bias,
                                               void* __restrict__ Cout,
                                               int K, int ldc, int mode) {
  __shared__ float4 lds_v[9216];  // 147456 B
  char* lds = (char*)lds_v;
  int t = threadIdx.x;
  int w = t >> 6, l = t & 63, c = l & 15, g = l >> 4;
  int wr = w >> 1, wc = w & 1;
  size_t m0 = (size_t)blockIdx.y * 256, n0 = (size_t)blockIdx.x * 128;
  const u16* Ab = A + m0 * K;
  const u16* Bb = BT + n0 * K;
  int KT = K >> 6;

  f32x4 zero4 = {0.f, 0.f, 0.f, 0.f};
  f32x4 acc[4][4];
#pragma unroll
  for (int a = 0; a < 4; ++a)
#pragma unroll
    for (int b2 = 0; b2 < 4; ++b2) acc[a][b2] = zero4;

#pragma unroll
  for (int pt = 0; pt < 2; ++pt) {
    int boff = pt * 49152;
    stage_half(Ab, K, pt * 64, lds + boff, w, l);
    stage_half(Ab + (size_t)128 * K, K, pt * 64, lds + boff + 16384, w, l);
    stage_half(Bb, K, pt * 64, lds + boff + 32768, w, l);
  }
  VMW(6);
  __builtin_amdgcn_s_barrier();

  for (int tt = 0; tt < KT; ++tt) {
    const char* Abuf = lds + (tt % 3) * 49152;
    const char* Bbuf = Abuf + 32768;
    int b2off = ((tt + 2) % 3) * 49152;
    int kt2 = (tt + 2) * 64;
    bool pf = (tt + 2 < KT);

    if (pf) {
      stage_half(Ab, K, kt2, lds + b2off, w, l);
      stage_half(Ab + (size_t)128 * K, K, kt2, lds + b2off + 16384, w, l);
    }
    {
      short8 bv[4], av[4];
#pragma unroll
      for (int nj = 0; nj < 4; ++nj) bv[nj] = ldfrag(Bbuf, wc * 64 + 16 * nj + c, g);
#pragma unroll
      for (int mi = 0; mi < 4; ++mi) av[mi] = ldfrag(Abuf, wr * 64 + 16 * mi + c, g);
      __builtin_amdgcn_s_setprio(1);
#pragma unroll
      for (int mi = 0; mi < 4; ++mi)
#pragma unroll
        for (int nj = 0; nj < 4; ++nj)
          acc[mi][nj] = __builtin_amdgcn_mfma_f32_16x16x32_bf16(av[mi], bv[nj], acc[mi][nj], 0, 0, 0);
      __builtin_amdgcn_s_setprio(0);
    }
    __builtin_amdgcn_s_barrier();

    if (pf) stage_half(Bb, K, kt2, lds + b2off + 32768, w, l);
    {
      short8 bv[4], av[4];
#pragma unroll
      for (int nj = 0; nj < 4; ++nj) bv[nj] = ldfrag(Bbuf, wc * 64 + 16 * nj + c, 4 + g);
#pragma unroll
      for (int mi = 0; mi < 4; ++mi) av[mi] = ldfrag(Abuf, wr * 64 + 16 * mi + c, 4 + g);
      __builtin_amdgcn_s_setprio(1);
#pragma unroll
      for (int mi = 0; mi < 4; ++mi)
#pragma unroll
        for (int nj = 0; nj < 4; ++nj)
          acc[mi][nj] = __builtin_amdgcn_mfma_f32_16x16x32_bf16(av[mi], bv[nj], acc[mi][nj], 0, 0, 0);
      __builtin_amdgcn_s_setprio(0);
    }
    if (tt + 1 < KT) {
      if (pf)
        VMW(6);
      else
        VMW(0);
      __builtin_amdgcn_s_barrier();
    }
  }

#pragma unroll
  for (int nj = 0; nj < 4; ++nj) {
    int col = (int)n0 + wc * 64 + 16 * nj + c;
    float bvv = bias[col];
#pragma unroll
    for (int mi = 0; mi < 4; ++mi) {
      size_t rbase = m0 + wr * 64 + 16 * mi + 4 * g;
#pragma unroll
      for (int r = 0; r < 4; ++r) {
        float f = acc[mi][nj][r] + bvv;
        if (mode == 1) f = 0.5f * f * (1.0f + erff(f * 0.70710678f));
        size_t oidx = (rbase + r) * (size_t)ldc + col;
        if (mode == 2)
          ((float*)Cout)[oidx] = f;
        else
          ((u16*)Cout)[oidx] = f2bf(f);
      }
    }
  }
}

// ---------------- sliding-window causal attention (pair-tile softmax) --------
// 1 wave per 32-query tile, no barriers. grid = 4096, block = 64.
// k-tiles processed in PAIRS (128 keys per online-softmax update): one
// max/sum shuffle-reduction and one o-rescale per 128 keys (halves LDS-pipe
// shuffle traffic). Odd tile counts: virtual second half fully masked
// (s = -1e30 -> p = 0; junk V reads are finite bf16 * 0 = 0).
__global__ __launch_bounds__(64, 3) void attn_kernel(const u16* __restrict__ qkv,
                                                     const u16* __restrict__ vT,
                                                     u16* __restrict__ comb) {
  int bid = blockIdx.x;
  int swz = ((bid & 7) << 9) + (bid >> 3);  // 4096/8 = 512 per XCD
  int qt = swz & 127, h = (swz >> 7) & 15, b = swz >> 11;
  int l = threadIdx.x, c = l & 15, g = l >> 4;
  int q0 = qt * 32;
  const u16* qb = qkv + (size_t)b * 4096 * 3072 + h * 64;
  const u16* kb = qb + 1024;
  const u16* vt = vT + (size_t)(b * 16 + h) * 64 * 4096;
  __shared__ u16 Pl[32 * 136];  // rows 0..31, 128 P cols, stride 136 (2-way banks)

  short8 qf[2][2];
#pragma unroll
  for (int mi = 0; mi < 2; ++mi)
#pragma unroll
    for (int kk = 0; kk < 2; ++kk)
      qf[mi][kk] = *reinterpret_cast<const short8*>(
          qb + (size_t)(q0 + 16 * mi + c) * 3072 + 32 * kk + 8 * g);

  f32x4 zero4 = {0.f, 0.f, 0.f, 0.f};
  f32x4 mfill = {-1e30f, -1e30f, -1e30f, -1e30f};
  f32x4 o[2][4];
  float mr[2][4], lr[2][4];
#pragma unroll
  for (int a = 0; a < 2; ++a)
#pragma unroll
    for (int d2 = 0; d2 < 4; ++d2) {
      o[a][d2] = zero4;
      mr[a][d2] = -1e30f;
      lr[a][d2] = 0.f;
    }

  int t_lo = (q0 >= 480) ? ((q0 - 480) >> 6) : 0;
  int t_hi = (q0 + 31) >> 6;
  for (int T = t_lo; T <= t_hi; T += 2) {
    f32x4 s[2][8];  // [mi][4*half + nj]

#pragma unroll
    for (int hh = 0; hh < 2; ++hh) {
      int tt = T + hh;
      if (tt <= t_hi) {
        int kt0 = tt * 64;
#pragma unroll
        for (int mi = 0; mi < 2; ++mi)
#pragma unroll
          for (int nj = 0; nj < 4; ++nj) s[mi][4 * hh + nj] = zero4;
#pragma unroll
        for (int kk = 0; kk < 2; ++kk) {
          short8 kf[4];
#pragma unroll
          for (int nj = 0; nj < 4; ++nj)
            kf[nj] = *reinterpret_cast<const short8*>(
                kb + (size_t)(kt0 + 16 * nj + c) * 3072 + 32 * kk + 8 * g);
#pragma unroll
          for (int mi = 0; mi < 2; ++mi)
#pragma unroll
            for (int nj = 0; nj < 4; ++nj)
              s[mi][4 * hh + nj] =
                  __builtin_amdgcn_mfma_f32_16x16x32_bf16(qf[mi][kk], kf[nj], s[mi][4 * hh + nj], 0, 0, 0);
        }
        bool mc = (tt == t_hi), mw = (tt == t_lo);
        if (mc | mw) {
#pragma unroll
          for (int mi = 0; mi < 2; ++mi)
#pragma unroll
            for (int nj = 0; nj < 4; ++nj)
#pragma unroll
              for (int r = 0; r < 4; ++r) {
                int qg = q0 + 16 * mi + 4 * g + r;
                int kg = kt0 + 16 * nj + c;
                if ((mc && kg > qg) || (mw && qg - kg >= 512)) s[mi][4 * hh + nj][r] = -1e30f;
              }
        }
      } else {
#pragma unroll
        for (int mi = 0; mi < 2; ++mi)
#pragma unroll
          for (int nj = 0; nj < 4; ++nj) s[mi][4 * hh + nj] = mfill;
      }
    }

    // online softmax over 128 keys (one reduction per row-slot)
#pragma unroll
    for (int mi = 0; mi < 2; ++mi)
#pragma unroll
      for (int r = 0; r < 4; ++r) {
        float tm = s[mi][0][r];
#pragma unroll
        for (int n2 = 1; n2 < 8; ++n2) tm = fmaxf(tm, s[mi][n2][r]);
        tm = redmax16(tm);
        float mn = fmaxf(mr[mi][r], tm);
        float a = __expf(mr[mi][r] - mn);
        mr[mi][r] = mn;
        float rs = 0.f;
        u16* pp = &Pl[(16 * mi + 4 * g + r) * 136 + c];
#pragma unroll
        for (int n2 = 0; n2 < 8; ++n2) {
          float p = __expf(s[mi][n2][r] - mn);
          rs += p;
          pp[16 * n2] = f2bf(p);  // imm-offset ds_write_b16
        }
        rs = redsum16(rs);
        lr[mi][r] = lr[mi][r] * a + rs;
#pragma unroll
        for (int dj = 0; dj < 4; ++dj) o[mi][dj][r] *= a;
      }

    // PV over 128 keys: 4 k-slices of 32
#pragma unroll
    for (int k2 = 0; k2 < 4; ++k2) {
      short8 pa[2];
#pragma unroll
      for (int mi = 0; mi < 2; ++mi)
        pa[mi] = *reinterpret_cast<const short8*>(&Pl[(16 * mi + c) * 136 + 32 * k2 + 8 * g]);
      short8 bv[4];
#pragma unroll
      for (int dj = 0; dj < 4; ++dj)
        bv[dj] = *reinterpret_cast<const short8*>(
            vt + (size_t)(16 * dj + c) * 4096 + T * 64 + 32 * k2 + 8 * g);
#pragma unroll
      for (int mi = 0; mi < 2; ++mi)
#pragma unroll
        for (int dj = 0; dj < 4; ++dj)
          o[mi][dj] = __builtin_amdgcn_mfma_f32_16x16x32_bf16(pa[mi], bv[dj], o[mi][dj], 0, 0, 0);
    }
  }

  u16* ob = comb + (size_t)(b * 4096 + q0) * 5120 + h * 64;
#pragma unroll
  for (int mi = 0; mi < 2; ++mi)
#pragma unroll
    for (int r = 0; r < 4; ++r) {
      float inv = __builtin_amdgcn_rcpf(lr[mi][r]);
#pragma unroll
      for (int dj = 0; dj < 4; ++dj)
        ob[(size_t)(16 * mi + 4 * g + r) * 5120 + 16 * dj + c] = f2bf(o[mi][dj][r] * inv);
    }
}

// ---------------- launch ----------------
extern "C" void kernel_launch(void* const* d_in, const int* in_sizes, int n_in,
                              void* d_out, int out_size, void* d_ws, size_t ws_size,
                              hipStream_t stream) {
  const float* x = (const float*)d_in[0];
  const float* sinp = (const float*)d_in[1];
  const float* cosp = (const float*)d_in[2];
  const float* norm_w = (const float*)d_in[3];
  const float* w_qkv = (const float*)d_in[4];
  const float* b_qkv = (const float*)d_in[5];
  const float* w_in = (const float*)d_in[6];
  const float* b_in = (const float*)d_in[7];
  const float* w_out = (const float*)d_in[8];
  const float* b_out = (const float*)d_in[9];
  float* out = (float*)d_out;

  char* ws = (char*)d_ws;
  u16* xn = (u16*)(ws);                        // 8192*1024*2      = 16,777,216
  u16* vT = (u16*)(ws);                        // aliases xn (xn dead after FF gemm); 32*64*4096*2 = 16,777,216
  u16* qkv = (u16*)(ws + 16777216);            // 8192*3072*2      = 50,331,648
  u16* comb = (u16*)(ws + 67108864);           // 8192*5120*2      = 83,886,080
  u16* wqkvT = (u16*)(ws + 150994944);         // 3072*1024*2      = 6,291,456
  u16* winT = (u16*)(ws + 157286400);          // 4096*1024*2      = 8,388,608
  u16* woutT = (u16*)(ws + 165675008);         // 1024*5120*2      = 10,485,760

  transpose_f32_bf16<<<dim3(3072 / 32, 1024 / 32), 256, 0, stream>>>(w_qkv, wqkvT, 1024, 3072);
  transpose_f32_bf16<<<dim3(4096 / 32, 1024 / 32), 256, 0, stream>>>(w_in, winT, 1024, 4096);
  transpose_f32_bf16<<<dim3(1024 / 32, 5120 / 32), 256, 0, stream>>>(w_out, woutT, 5120, 1024);

  rmsnorm_kernel<<<8192, 256, 0, stream>>>(x, norm_w, xn);

  // qkv = xn @ w_qkv + b_qkv   (bf16 out)
  gemm256<<<dim3(3072 / 128, 8192 / 256), 512, 0, stream>>>(xn, wqkvT, b_qkv, qkv, 1024, 3072, 0);

  rope_kernel<<<8192, 256, 0, stream>>>(qkv, sinp, cosp);

  // ff = gelu(xn @ w_in + b_in) -> comb cols [1024, 5120)  (last use of xn)
  gemm256<<<dim3(4096 / 128, 8192 / 256), 512, 0, stream>>>(xn, winT, b_in, comb + 1024, 1024, 5120, 1);

  // vT[b,h][d][s] = V  (into xn's region; xn dead after FF gemm)
  transpose_v<<<dim3(128, 2, 32), 256, 0, stream>>>(qkv, vT);

  attn_kernel<<<4096, 64, 0, stream>>>(qkv, vT, comb);

  // out = comb @ w_out + b_out  (f32 out)
  gemm256<<<dim3(1024 / 128, 8192 / 256), 512, 0, stream>>>(comb, woutT, b_out, out, 5120, 1024, 2);
}

// Round 15
// 415.739 us; speedup vs baseline: 1.0920x; 1.0920x over previous
//
#include <hip/hip_runtime.h>

typedef unsigned short u16;
typedef __attribute__((ext_vector_type(8))) short short8;
typedef __attribute__((ext_vector_type(4))) unsigned short u16x4;
typedef __attribute__((ext_vector_type(4))) float f32x4;

#define DEV __device__ __forceinline__
#define VMW(n) asm volatile("s_waitcnt vmcnt(" #n ")" ::: "memory")

DEV float bf2f(u16 u) { return __uint_as_float(((unsigned int)u) << 16); }
DEV u16 f2bf(float f) {
  unsigned int u = __float_as_uint(f);
  u += 0x7FFF + ((u >> 16) & 1);
  return (u16)(u >> 16);
}

DEV float redmax16(float v) {
  v = fmaxf(v, __shfl_xor(v, 1));
  v = fmaxf(v, __shfl_xor(v, 2));
  v = fmaxf(v, __shfl_xor(v, 4));
  v = fmaxf(v, __shfl_xor(v, 8));
  return v;
}
DEV float redsum16(float v) {
  v += __shfl_xor(v, 1);
  v += __shfl_xor(v, 2);
  v += __shfl_xor(v, 4);
  v += __shfl_xor(v, 8);
  return v;
}

// ---------------- transpose + cast f32 -> bf16, 32x32 tiles ----------------
__global__ __launch_bounds__(256) void transpose_f32_bf16(const float* __restrict__ in,
                                                          u16* __restrict__ out,
                                                          int R, int C) {
  __shared__ u16 tile[32][33];
  int tx = threadIdx.x & 31, ty = threadIdx.x >> 5;  // 32 x 8
  int r0 = blockIdx.y * 32, c0 = blockIdx.x * 32;
#pragma unroll
  for (int i = 0; i < 32; i += 8)
    tile[ty + i][tx] = f2bf(in[(size_t)(r0 + ty + i) * C + c0 + tx]);
  __syncthreads();
#pragma unroll
  for (int i = 0; i < 32; i += 8)
    out[(size_t)(c0 + ty + i) * R + r0 + tx] = tile[tx][ty + i];
}

// ---------------- transpose V third of qkv -> vT[b,h][64][4096] -------------
__global__ __launch_bounds__(256) void transpose_v(const u16* __restrict__ qkv,
                                                   u16* __restrict__ vT) {
  __shared__ u16 tile[32][33];
  int tx = threadIdx.x & 31, ty = threadIdx.x >> 5;  // 32 x 8
  int s0 = blockIdx.x * 32, d0 = blockIdx.y * 32;
  int bh = blockIdx.z;
  const u16* src = qkv + (size_t)(bh >> 4) * 4096 * 3072 + 2048 + (bh & 15) * 64;
#pragma unroll
  for (int i = 0; i < 32; i += 8)
    tile[ty + i][tx] = src[(size_t)(s0 + ty + i) * 3072 + d0 + tx];
  __syncthreads();
  u16* dst = vT + (size_t)bh * 64 * 4096;
#pragma unroll
  for (int i = 0; i < 32; i += 8)
    dst[(size_t)(d0 + ty + i) * 4096 + s0 + tx] = tile[tx][ty + i];
}

// ---------------- RMSNorm: 8192 rows x 1024, f32 in -> bf16 out ----------------
__global__ __launch_bounds__(256) void rmsnorm_kernel(const float* __restrict__ x,
                                                      const float* __restrict__ w,
                                                      u16* __restrict__ xn) {
  int row = blockIdx.x, t = threadIdx.x;
  const float4* xr = reinterpret_cast<const float4*>(x + (size_t)row * 1024);
  float4 v = xr[t];
  float ss = v.x * v.x + v.y * v.y + v.z * v.z + v.w * v.w;
#pragma unroll
  for (int d = 1; d < 64; d <<= 1) ss += __shfl_xor(ss, d);
  __shared__ float red[4];
  if ((t & 63) == 0) red[t >> 6] = ss;
  __syncthreads();
  float tot = red[0] + red[1] + red[2] + red[3];
  float inv = rsqrtf(tot * (1.0f / 1024.0f) + 1e-6f);
  float4 wv = reinterpret_cast<const float4*>(w)[t];
  u16x4 o;
  o[0] = f2bf(v.x * inv * wv.x);
  o[1] = f2bf(v.y * inv * wv.y);
  o[2] = f2bf(v.z * inv * wv.z);
  o[3] = f2bf(v.w * inv * wv.w);
  *reinterpret_cast<u16x4*>(xn + (size_t)row * 1024 + t * 4) = o;
}

// ------- RoPE in-place, vectorized: one block per qkv row; q scaled 0.125 ----
__global__ __launch_bounds__(256) void rope_kernel(u16* __restrict__ qkv,
                                                   const float* __restrict__ sp,
                                                   const float* __restrict__ cp) {
  int row = blockIdx.x;  // 8192 rows
  int t = threadIdx.x;
  int pos = row & 4095;
  int e0 = t * 8;
  float sc = (e0 < 1024) ? 0.125f : 1.0f;  // fold 1/sqrt(64) into q (exact)
  int d0 = e0 & 63;
  u16* p = qkv + (size_t)row * 3072 + e0;
  short8 v = *reinterpret_cast<const short8*>(p);
  float4 s01 = *reinterpret_cast<const float4*>(sp + pos * 64 + d0);
  float4 s23 = *reinterpret_cast<const float4*>(sp + pos * 64 + d0 + 4);
  float4 c01 = *reinterpret_cast<const float4*>(cp + pos * 64 + d0);
  float4 c23 = *reinterpret_cast<const float4*>(cp + pos * 64 + d0 + 4);
  short8 o;
  float xe, xo;
  xe = bf2f((u16)v[0]); xo = bf2f((u16)v[1]);
  o[0] = (short)f2bf((xe * c01.x - xo * s01.x) * sc);
  o[1] = (short)f2bf((xo * c01.y + xe * s01.y) * sc);
  xe = bf2f((u16)v[2]); xo = bf2f((u16)v[3]);
  o[2] = (short)f2bf((xe * c01.z - xo * s01.z) * sc);
  o[3] = (short)f2bf((xo * c01.w + xe * s01.w) * sc);
  xe = bf2f((u16)v[4]); xo = bf2f((u16)v[5]);
  o[4] = (short)f2bf((xe * c23.x - xo * s23.x) * sc);
  o[5] = (short)f2bf((xo * c23.y + xe * s23.y) * sc);
  xe = bf2f((u16)v[6]); xo = bf2f((u16)v[7]);
  o[6] = (short)f2bf((xe * c23.z - xo * s23.z) * sc);
  o[7] = (short)f2bf((xo * c23.w + xe * s23.w) * sc);
  *reinterpret_cast<short8*>(p) = o;
}

// ============ Pipelined GEMM (bench-R5/R9 exact): all three GEMMs ===========
// BM=256, BN=128, BK=64; 8 waves (4M x 2N). Triple-buffered LDS (144 KB),
// staging 1 tile ahead, counted vmcnt(6) at tile boundary, setprio, raw
// s_barrier, XOR-swizzled rows. mode 0: bf16; 1: bf16+GELU; 2: f32.
DEV void stage_half(const u16* __restrict__ gbase, int K, int kt, char* dst, int w, int l) {
#pragma unroll
  for (int j = 0; j < 2; ++j) {
    int s = w * 2 + j;
    int row = s * 8 + (l >> 3);
    int ksrc = ((l & 7) ^ (l >> 3)) << 3;
    const u16* src = gbase + (size_t)row * K + kt + ksrc;
    __builtin_amdgcn_global_load_lds(
        (const __attribute__((address_space(1))) unsigned int*)src,
        (__attribute__((address_space(3))) unsigned int*)(dst + s * 1024 + l * 16),
        16, 0, 0);
  }
}

DEV short8 ldfrag(const char* base, int row, int slot) {
  return *reinterpret_cast<const short8*>(base + row * 128 + (((slot ^ (row & 7)) << 4)));
}

__global__ __launch_bounds__(512) void gemm256(const u16* __restrict__ A,
                                               const u16* __restrict__ BT,
                                               const float* __restrict__ bias,
                                               void* __restrict__ Cout,
                                               int K, int ldc, int mode) {
  __shared__ float4 lds_v[9216];  // 147456 B
  char* lds = (char*)lds_v;
  int t = threadIdx.x;
  int w = t >> 6, l = t & 63, c = l & 15, g = l >> 4;
  int wr = w >> 1, wc = w & 1;
  size_t m0 = (size_t)blockIdx.y * 256, n0 = (size_t)blockIdx.x * 128;
  const u16* Ab = A + m0 * K;
  const u16* Bb = BT + n0 * K;
  int KT = K >> 6;

  f32x4 zero4 = {0.f, 0.f, 0.f, 0.f};
  f32x4 acc[4][4];
#pragma unroll
  for (int a = 0; a < 4; ++a)
#pragma unroll
    for (int b2 = 0; b2 < 4; ++b2) acc[a][b2] = zero4;

#pragma unroll
  for (int pt = 0; pt < 2; ++pt) {
    int boff = pt * 49152;
    stage_half(Ab, K, pt * 64, lds + boff, w, l);
    stage_half(Ab + (size_t)128 * K, K, pt * 64, lds + boff + 16384, w, l);
    stage_half(Bb, K, pt * 64, lds + boff + 32768, w, l);
  }
  VMW(6);
  __builtin_amdgcn_s_barrier();

  for (int tt = 0; tt < KT; ++tt) {
    const char* Abuf = lds + (tt % 3) * 49152;
    const char* Bbuf = Abuf + 32768;
    int b2off = ((tt + 2) % 3) * 49152;
    int kt2 = (tt + 2) * 64;
    bool pf = (tt + 2 < KT);

    if (pf) {
      stage_half(Ab, K, kt2, lds + b2off, w, l);
      stage_half(Ab + (size_t)128 * K, K, kt2, lds + b2off + 16384, w, l);
    }
    {
      short8 bv[4], av[4];
#pragma unroll
      for (int nj = 0; nj < 4; ++nj) bv[nj] = ldfrag(Bbuf, wc * 64 + 16 * nj + c, g);
#pragma unroll
      for (int mi = 0; mi < 4; ++mi) av[mi] = ldfrag(Abuf, wr * 64 + 16 * mi + c, g);
      __builtin_amdgcn_s_setprio(1);
#pragma unroll
      for (int mi = 0; mi < 4; ++mi)
#pragma unroll
        for (int nj = 0; nj < 4; ++nj)
          acc[mi][nj] = __builtin_amdgcn_mfma_f32_16x16x32_bf16(av[mi], bv[nj], acc[mi][nj], 0, 0, 0);
      __builtin_amdgcn_s_setprio(0);
    }
    __builtin_amdgcn_s_barrier();

    if (pf) stage_half(Bb, K, kt2, lds + b2off + 32768, w, l);
    {
      short8 bv[4], av[4];
#pragma unroll
      for (int nj = 0; nj < 4; ++nj) bv[nj] = ldfrag(Bbuf, wc * 64 + 16 * nj + c, 4 + g);
#pragma unroll
      for (int mi = 0; mi < 4; ++mi) av[mi] = ldfrag(Abuf, wr * 64 + 16 * mi + c, 4 + g);
      __builtin_amdgcn_s_setprio(1);
#pragma unroll
      for (int mi = 0; mi < 4; ++mi)
#pragma unroll
        for (int nj = 0; nj < 4; ++nj)
          acc[mi][nj] = __builtin_amdgcn_mfma_f32_16x16x32_bf16(av[mi], bv[nj], acc[mi][nj], 0, 0, 0);
      __builtin_amdgcn_s_setprio(0);
    }
    if (tt + 1 < KT) {
      if (pf)
        VMW(6);
      else
        VMW(0);
      __builtin_amdgcn_s_barrier();
    }
  }

#pragma unroll
  for (int nj = 0; nj < 4; ++nj) {
    int col = (int)n0 + wc * 64 + 16 * nj + c;
    float bvv = bias[col];
#pragma unroll
    for (int mi = 0; mi < 4; ++mi) {
      size_t rbase = m0 + wr * 64 + 16 * mi + 4 * g;
#pragma unroll
      for (int r = 0; r < 4; ++r) {
        float f = acc[mi][nj][r] + bvv;
        if (mode == 1) f = 0.5f * f * (1.0f + erff(f * 0.70710678f));
        size_t oidx = (rbase + r) * (size_t)ldc + col;
        if (mode == 2)
          ((float*)Cout)[oidx] = f;
        else
          ((u16*)Cout)[oidx] = f2bf(f);
      }
    }
  }
}

// ------------- sliding-window causal attention (register pipeline) ----------
// 1 wave per 32-query tile, no barriers. grid = 4096, block = 64.
// Latency fix (T14): at each tile, ISSUE next tile's K-frags and this tile's
// V-frags before QK^T/softmax; K[t+1] is consumed at the end-of-iteration
// rotate (in flight for the whole tile body), V[t] at PV (in flight across
// softmax). No launch_bounds VGPR cap — ILP over TLP (R14 lesson: (64,3)
// spilled the state and erased the win).
__global__ __launch_bounds__(64) void attn_kernel(const u16* __restrict__ qkv,
                                                  const u16* __restrict__ vT,
                                                  u16* __restrict__ comb) {
  int bid = blockIdx.x;
  int swz = ((bid & 7) << 9) + (bid >> 3);  // 4096/8 = 512 per XCD
  int qt = swz & 127, h = (swz >> 7) & 15, b = swz >> 11;
  int l = threadIdx.x, c = l & 15, g = l >> 4;
  int q0 = qt * 32;
  const u16* qb = qkv + (size_t)b * 4096 * 3072 + h * 64;
  const u16* kb = qb + 1024;
  const u16* vt = vT + (size_t)(b * 16 + h) * 64 * 4096;
  __shared__ u16 Pl[32 * 72];

  short8 qf[2][2];
#pragma unroll
  for (int mi = 0; mi < 2; ++mi)
#pragma unroll
    for (int kk = 0; kk < 2; ++kk)
      qf[mi][kk] = *reinterpret_cast<const short8*>(
          qb + (size_t)(q0 + 16 * mi + c) * 3072 + 32 * kk + 8 * g);

  f32x4 zero4 = {0.f, 0.f, 0.f, 0.f};
  f32x4 o[2][4];
  float mr[2][4], lr[2][4];
#pragma unroll
  for (int a = 0; a < 2; ++a)
#pragma unroll
    for (int d2 = 0; d2 < 4; ++d2) {
      o[a][d2] = zero4;
      mr[a][d2] = -1e30f;
      lr[a][d2] = 0.f;
    }

  int t_lo = (q0 >= 480) ? ((q0 - 480) >> 6) : 0;
  int t_hi = (q0 + 31) >> 6;

  short8 kfc[2][4], kfn[2][4], bv[2][4];
  // preload K-frags of the first tile
#pragma unroll
  for (int kk = 0; kk < 2; ++kk)
#pragma unroll
    for (int nj = 0; nj < 4; ++nj)
      kfc[kk][nj] = *reinterpret_cast<const short8*>(
          kb + (size_t)(t_lo * 64 + 16 * nj + c) * 3072 + 32 * kk + 8 * g);

  for (int tt = t_lo; tt <= t_hi; ++tt) {
    int kt0 = tt * 64;

    // issue V[t] loads (consumed at PV, after softmax)
#pragma unroll
    for (int kk = 0; kk < 2; ++kk)
#pragma unroll
      for (int dj = 0; dj < 4; ++dj)
        bv[kk][dj] = *reinterpret_cast<const short8*>(
            vt + (size_t)(16 * dj + c) * 4096 + kt0 + 32 * kk + 8 * g);

    // issue K[t+1] loads (consumed at the rotate, after PV)
    if (tt < t_hi) {
#pragma unroll
      for (int kk = 0; kk < 2; ++kk)
#pragma unroll
        for (int nj = 0; nj < 4; ++nj)
          kfn[kk][nj] = *reinterpret_cast<const short8*>(
              kb + (size_t)(kt0 + 64 + 16 * nj + c) * 3072 + 32 * kk + 8 * g);
    }

    // QK^T with current (pre-loaded) K frags
    f32x4 s[2][4];
#pragma unroll
    for (int a = 0; a < 2; ++a)
#pragma unroll
      for (int d2 = 0; d2 < 4; ++d2) s[a][d2] = zero4;
#pragma unroll
    for (int kk = 0; kk < 2; ++kk)
#pragma unroll
      for (int mi = 0; mi < 2; ++mi)
#pragma unroll
        for (int nj = 0; nj < 4; ++nj)
          s[mi][nj] = __builtin_amdgcn_mfma_f32_16x16x32_bf16(qf[mi][kk], kfc[kk][nj], s[mi][nj], 0, 0, 0);

    // mask only on the boundary tiles (wave-uniform branch)
    bool mc = (tt == t_hi), mw = (tt == t_lo);
    if (mc | mw) {
#pragma unroll
      for (int mi = 0; mi < 2; ++mi)
#pragma unroll
        for (int nj = 0; nj < 4; ++nj)
#pragma unroll
          for (int r = 0; r < 4; ++r) {
            int qg = q0 + 16 * mi + 4 * g + r;
            int kg = kt0 + 16 * nj + c;
            if ((mc && kg > qg) || (mw && qg - kg >= 512)) s[mi][nj][r] = -1e30f;
          }
    }

#pragma unroll
    for (int mi = 0; mi < 2; ++mi)
#pragma unroll
      for (int r = 0; r < 4; ++r) {
        float tm = fmaxf(fmaxf(s[mi][0][r], s[mi][1][r]), fmaxf(s[mi][2][r], s[mi][3][r]));
        tm = redmax16(tm);
        float mn = fmaxf(mr[mi][r], tm);
        float a = __expf(mr[mi][r] - mn);
        mr[mi][r] = mn;
        float rs = 0.f;
        u16* pp = &Pl[(16 * mi + 4 * g + r) * 72 + c];
#pragma unroll
        for (int nj = 0; nj < 4; ++nj) {
          float p = __expf(s[mi][nj][r] - mn);
          rs += p;
          pp[16 * nj] = f2bf(p);  // natural k order, imm-offset ds_write_b16
        }
        rs = redsum16(rs);
        lr[mi][r] = lr[mi][r] * a + rs;
#pragma unroll
        for (int dj = 0; dj < 4; ++dj) o[mi][dj][r] *= a;
      }

    // PV: A-frag from Pl, B-frag = V regs issued before softmax
#pragma unroll
    for (int kk = 0; kk < 2; ++kk) {
      short8 pa[2];
#pragma unroll
      for (int mi = 0; mi < 2; ++mi)
        pa[mi] = *reinterpret_cast<const short8*>(&Pl[(16 * mi + c) * 72 + 32 * kk + 8 * g]);
#pragma unroll
      for (int mi = 0; mi < 2; ++mi)
#pragma unroll
        for (int dj = 0; dj < 4; ++dj)
          o[mi][dj] = __builtin_amdgcn_mfma_f32_16x16x32_bf16(pa[mi], bv[kk][dj], o[mi][dj], 0, 0, 0);
    }

    // rotate: consume K[t+1] loads (they were in flight the whole tile)
    if (tt < t_hi) {
#pragma unroll
      for (int kk = 0; kk < 2; ++kk)
#pragma unroll
        for (int nj = 0; nj < 4; ++nj) kfc[kk][nj] = kfn[kk][nj];
    }
  }

  u16* ob = comb + (size_t)(b * 4096 + q0) * 5120 + h * 64;
#pragma unroll
  for (int mi = 0; mi < 2; ++mi)
#pragma unroll
    for (int r = 0; r < 4; ++r) {
      float inv = __builtin_amdgcn_rcpf(lr[mi][r]);
#pragma unroll
      for (int dj = 0; dj < 4; ++dj)
        ob[(size_t)(16 * mi + 4 * g + r) * 5120 + 16 * dj + c] = f2bf(o[mi][dj][r] * inv);
    }
}

// ---------------- launch ----------------
extern "C" void kernel_launch(void* const* d_in, const int* in_sizes, int n_in,
                              void* d_out, int out_size, void* d_ws, size_t ws_size,
                              hipStream_t stream) {
  const float* x = (const float*)d_in[0];
  const float* sinp = (const float*)d_in[1];
  const float* cosp = (const float*)d_in[2];
  const float* norm_w = (const float*)d_in[3];
  const float* w_qkv = (const float*)d_in[4];
  const float* b_qkv = (const float*)d_in[5];
  const float* w_in = (const float*)d_in[6];
  const float* b_in = (const float*)d_in[7];
  const float* w_out = (const float*)d_in[8];
  const float* b_out = (const float*)d_in[9];
  float* out = (float*)d_out;

  char* ws = (char*)d_ws;
  u16* xn = (u16*)(ws);                        // 8192*1024*2      = 16,777,216
  u16* vT = (u16*)(ws);                        // aliases xn (xn dead after FF gemm)
  u16* qkv = (u16*)(ws + 16777216);            // 8192*3072*2      = 50,331,648
  u16* comb = (u16*)(ws + 67108864);           // 8192*5120*2      = 83,886,080
  u16* wqkvT = (u16*)(ws + 150994944);         // 3072*1024*2      = 6,291,456
  u16* winT = (u16*)(ws + 157286400);          // 4096*1024*2      = 8,388,608
  u16* woutT = (u16*)(ws + 165675008);         // 1024*5120*2      = 10,485,760

  transpose_f32_bf16<<<dim3(3072 / 32, 1024 / 32), 256, 0, stream>>>(w_qkv, wqkvT, 1024, 3072);
  transpose_f32_bf16<<<dim3(4096 / 32, 1024 / 32), 256, 0, stream>>>(w_in, winT, 1024, 4096);
  transpose_f32_bf16<<<dim3(1024 / 32, 5120 / 32), 256, 0, stream>>>(w_out, woutT, 5120, 1024);

  rmsnorm_kernel<<<8192, 256, 0, stream>>>(x, norm_w, xn);

  // qkv = xn @ w_qkv + b_qkv   (bf16 out)
  gemm256<<<dim3(3072 / 128, 8192 / 256), 512, 0, stream>>>(xn, wqkvT, b_qkv, qkv, 1024, 3072, 0);

  rope_kernel<<<8192, 256, 0, stream>>>(qkv, sinp, cosp);

  // ff = gelu(xn @ w_in + b_in) -> comb cols [1024, 5120)  (last use of xn)
  gemm256<<<dim3(4096 / 128, 8192 / 256), 512, 0, stream>>>(xn, winT, b_in, comb + 1024, 1024, 5120, 1);

  // vT[b,h][d][s] = V  (into xn's region; xn dead after FF gemm)
  transpose_v<<<dim3(128, 2, 32), 256, 0, stream>>>(qkv, vT);

  attn_kernel<<<4096, 64, 0, stream>>>(qkv, vT, comb);

  // out = comb @ w_out + b_out  (f32 out)
  gemm256<<<dim3(1024 / 128, 8192 / 256), 512, 0, stream>>>(comb, woutT, b_out, out, 5120, 1024, 2);
}

// Round 16
// 391.272 us; speedup vs baseline: 1.1603x; 1.0625x over previous
//
#include <hip/hip_runtime.h>

typedef unsigned short u16;
typedef __attribute__((ext_vector_type(8))) short short8;
typedef __attribute__((ext_vector_type(4))) unsigned short u16x4;
typedef __attribute__((ext_vector_type(4))) float f32x4;

#define DEV __device__ __forceinline__
#define VMW(n) asm volatile("s_waitcnt vmcnt(" #n ")" ::: "memory")

DEV float bf2f(u16 u) { return __uint_as_float(((unsigned int)u) << 16); }
DEV u16 f2bf(float f) {
  unsigned int u = __float_as_uint(f);
  u += 0x7FFF + ((u >> 16) & 1);
  return (u16)(u >> 16);
}

DEV float redmax16(float v) {
  v = fmaxf(v, __shfl_xor(v, 1));
  v = fmaxf(v, __shfl_xor(v, 2));
  v = fmaxf(v, __shfl_xor(v, 4));
  v = fmaxf(v, __shfl_xor(v, 8));
  return v;
}
DEV float redsum16(float v) {
  v += __shfl_xor(v, 1);
  v += __shfl_xor(v, 2);
  v += __shfl_xor(v, 4);
  v += __shfl_xor(v, 8);
  return v;
}

// ---------------- transpose + cast f32 -> bf16, 32x32 tiles ----------------
__global__ __launch_bounds__(256) void transpose_f32_bf16(const float* __restrict__ in,
                                                          u16* __restrict__ out,
                                                          int R, int C) {
  __shared__ u16 tile[32][33];
  int tx = threadIdx.x & 31, ty = threadIdx.x >> 5;  // 32 x 8
  int r0 = blockIdx.y * 32, c0 = blockIdx.x * 32;
#pragma unroll
  for (int i = 0; i < 32; i += 8)
    tile[ty + i][tx] = f2bf(in[(size_t)(r0 + ty + i) * C + c0 + tx]);
  __syncthreads();
#pragma unroll
  for (int i = 0; i < 32; i += 8)
    out[(size_t)(c0 + ty + i) * R + r0 + tx] = tile[tx][ty + i];
}

// ---------------- RMSNorm: 8192 rows x 1024, f32 in -> bf16 out ----------------
__global__ __launch_bounds__(256) void rmsnorm_kernel(const float* __restrict__ x,
                                                      const float* __restrict__ w,
                                                      u16* __restrict__ xn) {
  int row = blockIdx.x, t = threadIdx.x;
  const float4* xr = reinterpret_cast<const float4*>(x + (size_t)row * 1024);
  float4 v = xr[t];
  float ss = v.x * v.x + v.y * v.y + v.z * v.z + v.w * v.w;
#pragma unroll
  for (int d = 1; d < 64; d <<= 1) ss += __shfl_xor(ss, d);
  __shared__ float red[4];
  if ((t & 63) == 0) red[t >> 6] = ss;
  __syncthreads();
  float tot = red[0] + red[1] + red[2] + red[3];
  float inv = rsqrtf(tot * (1.0f / 1024.0f) + 1e-6f);
  float4 wv = reinterpret_cast<const float4*>(w)[t];
  u16x4 o;
  o[0] = f2bf(v.x * inv * wv.x);
  o[1] = f2bf(v.y * inv * wv.y);
  o[2] = f2bf(v.z * inv * wv.z);
  o[3] = f2bf(v.w * inv * wv.w);
  *reinterpret_cast<u16x4*>(xn + (size_t)row * 1024 + t * 4) = o;
}

// ============ Pipelined GEMM (bench-R5/R9 schedule): all three GEMMs ========
// BM=256, BN=128, BK=64; 8 waves (4M x 2N). Triple-buffered LDS (144 KB),
// staging 1 tile ahead, counted vmcnt(6) at tile boundary, setprio, raw
// s_barrier, XOR-swizzled rows.
// mode 1: bf16+GELU; 2: f32; 3: QKV fused epilogue (rope+scale on q/k cols
// into qk[ldc=2048]; V cols ([2048,3072)) written directly to vT[b,h][d][s]).
DEV void stage_half(const u16* __restrict__ gbase, int K, int kt, char* dst, int w, int l) {
#pragma unroll
  for (int j = 0; j < 2; ++j) {
    int s = w * 2 + j;
    int row = s * 8 + (l >> 3);
    int ksrc = ((l & 7) ^ (l >> 3)) << 3;
    const u16* src = gbase + (size_t)row * K + kt + ksrc;
    __builtin_amdgcn_global_load_lds(
        (const __attribute__((address_space(1))) unsigned int*)src,
        (__attribute__((address_space(3))) unsigned int*)(dst + s * 1024 + l * 16),
        16, 0, 0);
  }
}

DEV short8 ldfrag(const char* base, int row, int slot) {
  return *reinterpret_cast<const short8*>(base + row * 128 + (((slot ^ (row & 7)) << 4)));
}

__global__ __launch_bounds__(512) void gemm256(const u16* __restrict__ A,
                                               const u16* __restrict__ BT,
                                               const float* __restrict__ bias,
                                               void* __restrict__ Cout,
                                               u16* __restrict__ vTout,
                                               const float* __restrict__ sp,
                                               const float* __restrict__ cp,
                                               int K, int ldc, int mode) {
  __shared__ float4 lds_v[9216];  // 147456 B
  char* lds = (char*)lds_v;
  int t = threadIdx.x;
  int w = t >> 6, l = t & 63, c = l & 15, g = l >> 4;
  int wr = w >> 1, wc = w & 1;
  size_t m0 = (size_t)blockIdx.y * 256, n0 = (size_t)blockIdx.x * 128;
  const u16* Ab = A + m0 * K;
  const u16* Bb = BT + n0 * K;
  int KT = K >> 6;

  f32x4 zero4 = {0.f, 0.f, 0.f, 0.f};
  f32x4 acc[4][4];
#pragma unroll
  for (int a = 0; a < 4; ++a)
#pragma unroll
    for (int b2 = 0; b2 < 4; ++b2) acc[a][b2] = zero4;

#pragma unroll
  for (int pt = 0; pt < 2; ++pt) {
    int boff = pt * 49152;
    stage_half(Ab, K, pt * 64, lds + boff, w, l);
    stage_half(Ab + (size_t)128 * K, K, pt * 64, lds + boff + 16384, w, l);
    stage_half(Bb, K, pt * 64, lds + boff + 32768, w, l);
  }
  VMW(6);
  __builtin_amdgcn_s_barrier();

  for (int tt = 0; tt < KT; ++tt) {
    const char* Abuf = lds + (tt % 3) * 49152;
    const char* Bbuf = Abuf + 32768;
    int b2off = ((tt + 2) % 3) * 49152;
    int kt2 = (tt + 2) * 64;
    bool pf = (tt + 2 < KT);

    if (pf) {
      stage_half(Ab, K, kt2, lds + b2off, w, l);
      stage_half(Ab + (size_t)128 * K, K, kt2, lds + b2off + 16384, w, l);
    }
    {
      short8 bv[4], av[4];
#pragma unroll
      for (int nj = 0; nj < 4; ++nj) bv[nj] = ldfrag(Bbuf, wc * 64 + 16 * nj + c, g);
#pragma unroll
      for (int mi = 0; mi < 4; ++mi) av[mi] = ldfrag(Abuf, wr * 64 + 16 * mi + c, g);
      __builtin_amdgcn_s_setprio(1);
#pragma unroll
      for (int mi = 0; mi < 4; ++mi)
#pragma unroll
        for (int nj = 0; nj < 4; ++nj)
          acc[mi][nj] = __builtin_amdgcn_mfma_f32_16x16x32_bf16(av[mi], bv[nj], acc[mi][nj], 0, 0, 0);
      __builtin_amdgcn_s_setprio(0);
    }
    __builtin_amdgcn_s_barrier();

    if (pf) stage_half(Bb, K, kt2, lds + b2off + 32768, w, l);
    {
      short8 bv[4], av[4];
#pragma unroll
      for (int nj = 0; nj < 4; ++nj) bv[nj] = ldfrag(Bbuf, wc * 64 + 16 * nj + c, 4 + g);
#pragma unroll
      for (int mi = 0; mi < 4; ++mi) av[mi] = ldfrag(Abuf, wr * 64 + 16 * mi + c, 4 + g);
      __builtin_amdgcn_s_setprio(1);
#pragma unroll
      for (int mi = 0; mi < 4; ++mi)
#pragma unroll
        for (int nj = 0; nj < 4; ++nj)
          acc[mi][nj] = __builtin_amdgcn_mfma_f32_16x16x32_bf16(av[mi], bv[nj], acc[mi][nj], 0, 0, 0);
      __builtin_amdgcn_s_setprio(0);
    }
    if (tt + 1 < KT) {
      if (pf)
        VMW(6);
      else
        VMW(0);
      __builtin_amdgcn_s_barrier();
    }
  }

  // ---- epilogue ----
  if (mode == 3) {
    bool blockV = (n0 >= 2048);  // block-uniform: 2048 % 128 == 0
    if (!blockV) {
      // q/k columns: bias, then rope (partner via shfl_xor lane^1), then q-scale
#pragma unroll
      for (int nj = 0; nj < 4; ++nj) {
        int col = (int)n0 + wc * 64 + 16 * nj + c;
        float bvv = bias[col];
        float sgn = (col & 1) ? 1.0f : -1.0f;
        float scq = (col < 1024) ? 0.125f : 1.0f;
        int d = col & 63;
#pragma unroll
        for (int mi = 0; mi < 4; ++mi) {
          size_t rbase = m0 + wr * 64 + 16 * mi + 4 * g;
#pragma unroll
          for (int r = 0; r < 4; ++r) {
            float fb = acc[mi][nj][r] + bvv;
            float fp = __shfl_xor(fb, 1);
            int pos = (int)((rbase + r) & 4095);
            float sv = sp[pos * 64 + d];
            float cv = cp[pos * 64 + d];
            ((u16*)Cout)[(rbase + r) * (size_t)ldc + col] = f2bf((fb * cv + sgn * fp * sv) * scq);
          }
        }
      }
    } else {
      // V columns: bias only, write directly to vT[b,h][d][s]
      int b16 = ((int)(m0 >> 12)) * 16;
#pragma unroll
      for (int nj = 0; nj < 4; ++nj) {
        int col = (int)n0 + wc * 64 + 16 * nj + c;
        float bvv = bias[col];
        int cv2 = col - 2048;
        int h = cv2 >> 6, d = cv2 & 63;
        u16* vb = vTout + ((size_t)(b16 + h)) * 262144 + (size_t)d * 4096;
#pragma unroll
        for (int mi = 0; mi < 4; ++mi) {
          size_t rbase = m0 + wr * 64 + 16 * mi + 4 * g;
          int s0 = (int)(rbase & 4095);
          u16x4 pk;
#pragma unroll
          for (int r = 0; r < 4; ++r) pk[r] = f2bf(acc[mi][nj][r] + bvv);
          *reinterpret_cast<u16x4*>(vb + s0) = pk;
        }
      }
    }
    return;
  }

#pragma unroll
  for (int nj = 0; nj < 4; ++nj) {
    int col = (int)n0 + wc * 64 + 16 * nj + c;
    float bvv = bias[col];
#pragma unroll
    for (int mi = 0; mi < 4; ++mi) {
      size_t rbase = m0 + wr * 64 + 16 * mi + 4 * g;
#pragma unroll
      for (int r = 0; r < 4; ++r) {
        float f = acc[mi][nj][r] + bvv;
        if (mode == 1) f = 0.5f * f * (1.0f + erff(f * 0.70710678f));
        size_t oidx = (rbase + r) * (size_t)ldc + col;
        if (mode == 2)
          ((float*)Cout)[oidx] = f;
        else
          ((u16*)Cout)[oidx] = f2bf(f);
      }
    }
  }
}

// ------------- sliding-window causal attention (register pipeline) ----------
// 1 wave per 32-query tile, no barriers. grid = 4096, block = 64.
// qk rows: [q(1024)|k(1024)], stride 2048, pre-roped, q pre-scaled 0.125.
// K[t+1] and V[t] issued early, consumed late (T14). No VGPR cap.
__global__ __launch_bounds__(64) void attn_kernel(const u16* __restrict__ qk,
                                                  const u16* __restrict__ vT,
                                                  u16* __restrict__ comb) {
  int bid = blockIdx.x;
  int swz = ((bid & 7) << 9) + (bid >> 3);  // 4096/8 = 512 per XCD
  int qt = swz & 127, h = (swz >> 7) & 15, b = swz >> 11;
  int l = threadIdx.x, c = l & 15, g = l >> 4;
  int q0 = qt * 32;
  const u16* qb = qk + (size_t)b * 4096 * 2048 + h * 64;
  const u16* kb = qb + 1024;
  const u16* vt = vT + (size_t)(b * 16 + h) * 64 * 4096;
  __shared__ u16 Pl[32 * 72];

  short8 qf[2][2];
#pragma unroll
  for (int mi = 0; mi < 2; ++mi)
#pragma unroll
    for (int kk = 0; kk < 2; ++kk)
      qf[mi][kk] = *reinterpret_cast<const short8*>(
          qb + (size_t)(q0 + 16 * mi + c) * 2048 + 32 * kk + 8 * g);

  f32x4 zero4 = {0.f, 0.f, 0.f, 0.f};
  f32x4 o[2][4];
  float mr[2][4], lr[2][4];
#pragma unroll
  for (int a = 0; a < 2; ++a)
#pragma unroll
    for (int d2 = 0; d2 < 4; ++d2) {
      o[a][d2] = zero4;
      mr[a][d2] = -1e30f;
      lr[a][d2] = 0.f;
    }

  int t_lo = (q0 >= 480) ? ((q0 - 480) >> 6) : 0;
  int t_hi = (q0 + 31) >> 6;

  short8 kfc[2][4], kfn[2][4], bv[2][4];
  // preload K-frags of the first tile
#pragma unroll
  for (int kk = 0; kk < 2; ++kk)
#pragma unroll
    for (int nj = 0; nj < 4; ++nj)
      kfc[kk][nj] = *reinterpret_cast<const short8*>(
          kb + (size_t)(t_lo * 64 + 16 * nj + c) * 2048 + 32 * kk + 8 * g);

  for (int tt = t_lo; tt <= t_hi; ++tt) {
    int kt0 = tt * 64;

    // issue V[t] loads (consumed at PV, after softmax)
#pragma unroll
    for (int kk = 0; kk < 2; ++kk)
#pragma unroll
      for (int dj = 0; dj < 4; ++dj)
        bv[kk][dj] = *reinterpret_cast<const short8*>(
            vt + (size_t)(16 * dj + c) * 4096 + kt0 + 32 * kk + 8 * g);

    // issue K[t+1] loads (consumed at the rotate, after PV)
    if (tt < t_hi) {
#pragma unroll
      for (int kk = 0; kk < 2; ++kk)
#pragma unroll
        for (int nj = 0; nj < 4; ++nj)
          kfn[kk][nj] = *reinterpret_cast<const short8*>(
              kb + (size_t)(kt0 + 64 + 16 * nj + c) * 2048 + 32 * kk + 8 * g);
    }

    // QK^T with current (pre-loaded) K frags
    f32x4 s[2][4];
#pragma unroll
    for (int a = 0; a < 2; ++a)
#pragma unroll
      for (int d2 = 0; d2 < 4; ++d2) s[a][d2] = zero4;
#pragma unroll
    for (int kk = 0; kk < 2; ++kk)
#pragma unroll
      for (int mi = 0; mi < 2; ++mi)
#pragma unroll
        for (int nj = 0; nj < 4; ++nj)
          s[mi][nj] = __builtin_amdgcn_mfma_f32_16x16x32_bf16(qf[mi][kk], kfc[kk][nj], s[mi][nj], 0, 0, 0);

    // mask only on the boundary tiles (wave-uniform branch)
    bool mc = (tt == t_hi), mw = (tt == t_lo);
    if (mc | mw) {
#pragma unroll
      for (int mi = 0; mi < 2; ++mi)
#pragma unroll
        for (int nj = 0; nj < 4; ++nj)
#pragma unroll
          for (int r = 0; r < 4; ++r) {
            int qg = q0 + 16 * mi + 4 * g + r;
            int kg = kt0 + 16 * nj + c;
            if ((mc && kg > qg) || (mw && qg - kg >= 512)) s[mi][nj][r] = -1e30f;
          }
    }

#pragma unroll
    for (int mi = 0; mi < 2; ++mi)
#pragma unroll
      for (int r = 0; r < 4; ++r) {
        float tm = fmaxf(fmaxf(s[mi][0][r], s[mi][1][r]), fmaxf(s[mi][2][r], s[mi][3][r]));
        tm = redmax16(tm);
        float mn = fmaxf(mr[mi][r], tm);
        float a = __expf(mr[mi][r] - mn);
        mr[mi][r] = mn;
        float rs = 0.f;
        u16* pp = &Pl[(16 * mi + 4 * g + r) * 72 + c];
#pragma unroll
        for (int nj = 0; nj < 4; ++nj) {
          float p = __expf(s[mi][nj][r] - mn);
          rs += p;
          pp[16 * nj] = f2bf(p);  // natural k order, imm-offset ds_write_b16
        }
        rs = redsum16(rs);
        lr[mi][r] = lr[mi][r] * a + rs;
#pragma unroll
        for (int dj = 0; dj < 4; ++dj) o[mi][dj][r] *= a;
      }

    // PV: A-frag from Pl, B-frag = V regs issued before softmax
#pragma unroll
    for (int kk = 0; kk < 2; ++kk) {
      short8 pa[2];
#pragma unroll
      for (int mi = 0; mi < 2; ++mi)
        pa[mi] = *reinterpret_cast<const short8*>(&Pl[(16 * mi + c) * 72 + 32 * kk + 8 * g]);
#pragma unroll
      for (int mi = 0; mi < 2; ++mi)
#pragma unroll
        for (int dj = 0; dj < 4; ++dj)
          o[mi][dj] = __builtin_amdgcn_mfma_f32_16x16x32_bf16(pa[mi], bv[kk][dj], o[mi][dj], 0, 0, 0);
    }

    // rotate: consume K[t+1] loads (they were in flight the whole tile)
    if (tt < t_hi) {
#pragma unroll
      for (int kk = 0; kk < 2; ++kk)
#pragma unroll
        for (int nj = 0; nj < 4; ++nj) kfc[kk][nj] = kfn[kk][nj];
    }
  }

  u16* ob = comb + (size_t)(b * 4096 + q0) * 5120 + h * 64;
#pragma unroll
  for (int mi = 0; mi < 2; ++mi)
#pragma unroll
    for (int r = 0; r < 4; ++r) {
      float inv = __builtin_amdgcn_rcpf(lr[mi][r]);
#pragma unroll
      for (int dj = 0; dj < 4; ++dj)
        ob[(size_t)(16 * mi + 4 * g + r) * 5120 + 16 * dj + c] = f2bf(o[mi][dj][r] * inv);
    }
}

// ---------------- launch ----------------
extern "C" void kernel_launch(void* const* d_in, const int* in_sizes, int n_in,
                              void* d_out, int out_size, void* d_ws, size_t ws_size,
                              hipStream_t stream) {
  const float* x = (const float*)d_in[0];
  const float* sinp = (const float*)d_in[1];
  const float* cosp = (const float*)d_in[2];
  const float* norm_w = (const float*)d_in[3];
  const float* w_qkv = (const float*)d_in[4];
  const float* b_qkv = (const float*)d_in[5];
  const float* w_in = (const float*)d_in[6];
  const float* b_in = (const float*)d_in[7];
  const float* w_out = (const float*)d_in[8];
  const float* b_out = (const float*)d_in[9];
  float* out = (float*)d_out;

  char* ws = (char*)d_ws;
  u16* xn = (u16*)(ws);                        // 8192*1024*2      = 16,777,216
  u16* qk = (u16*)(ws + 16777216);             // 8192*2048*2      = 33,554,432
  u16* vT = (u16*)(ws + 50331648);             // 32*64*4096*2     = 16,777,216
  u16* comb = (u16*)(ws + 67108864);           // 8192*5120*2      = 83,886,080
  u16* wqkvT = (u16*)(ws + 150994944);         // 3072*1024*2      = 6,291,456
  u16* winT = (u16*)(ws + 157286400);          // 4096*1024*2      = 8,388,608
  u16* woutT = (u16*)(ws + 165675008);         // 1024*5120*2      = 10,485,760

  transpose_f32_bf16<<<dim3(3072 / 32, 1024 / 32), 256, 0, stream>>>(w_qkv, wqkvT, 1024, 3072);
  transpose_f32_bf16<<<dim3(4096 / 32, 1024 / 32), 256, 0, stream>>>(w_in, winT, 1024, 4096);
  transpose_f32_bf16<<<dim3(1024 / 32, 5120 / 32), 256, 0, stream>>>(w_out, woutT, 5120, 1024);

  rmsnorm_kernel<<<8192, 256, 0, stream>>>(x, norm_w, xn);

  // qkv GEMM, fused epilogue: q/k -> rope+scale -> qk[2048]; V -> vT directly
  gemm256<<<dim3(3072 / 128, 8192 / 256), 512, 0, stream>>>(
      xn, wqkvT, b_qkv, qk, vT, sinp, cosp, 1024, 2048, 3);

  // ff = gelu(xn @ w_in + b_in) -> comb cols [1024, 5120)  (last use of xn)
  gemm256<<<dim3(4096 / 128, 8192 / 256), 512, 0, stream>>>(
      xn, winT, b_in, comb + 1024, nullptr, nullptr, nullptr, 1024, 5120, 1);

  attn_kernel<<<4096, 64, 0, stream>>>(qk, vT, comb);

  // out = comb @ w_out + b_out  (f32 out)
  gemm256<<<dim3(1024 / 128, 8192 / 256), 512, 0, stream>>>(
      comb, woutT, b_out, out, nullptr, nullptr, nullptr, 5120, 1024, 2);
}